// Round 9
// baseline (667.576 us; speedup 1.0000x reference)
//
#include <hip/hip_runtime.h>
#include <cstdint>
#include <cstddef>

static constexpr int M = 4096, K = 2048, N = 8192;
static constexpr int KBLK = K / 128;  // 16 k-blocks of the quant scheme

#define GLOBAL_AS __attribute__((address_space(1)))
#define LDS_AS    __attribute__((address_space(3)))

typedef float f32x4 __attribute__((ext_vector_type(4)));
typedef int   i32x4 __attribute__((ext_vector_type(4)));
typedef int   i32x8 __attribute__((ext_vector_type(8)));

// ---------- numerics helpers (fallback path) ----------

__device__ inline float fp8_e4m3_rne(float a) {
    float mag = fminf(fabsf(a), 448.0f);
    float r;
    if (mag < 0.015625f) {                       // below 2^-6: subnormal quantum 2^-9
        r = rintf(mag * 512.0f) * (1.0f / 512.0f);
    } else {
        uint32_t u = __float_as_uint(mag);
        u = (u + ((u >> 20) & 1u) + 0x7FFFFu) & 0xFFF00000u;   // RNE to 3 mantissa bits
        r = fminf(__uint_as_float(u), 448.0f);
    }
    return copysignf(r, a);
}

// ---------- quant kernels: f32 -> raw fp8 e4m3 bytes ----------

// x: per (row, 128-kblock) scale. Writes fp8 bytes + TRANSPOSED scales sxT[kb][m].
__global__ void quant_x_kernel(const float* __restrict__ x, uint8_t* __restrict__ xq,
                               float* __restrict__ sxT) {
    int task = blockIdx.x * 8 + (threadIdx.x >> 5);   // 32 lanes per (row,kb) task
    int sub  = threadIdx.x & 31;
    int row = task >> 4;           // KBLK = 16
    int kb  = task & 15;
    const float* p = x + (size_t)row * K + kb * 128 + sub * 4;
    float4 v = *reinterpret_cast<const float4*>(p);
    float amax = fmaxf(fmaxf(fabsf(v.x), fabsf(v.y)), fmaxf(fabsf(v.z), fabsf(v.w)));
    #pragma unroll
    for (int off = 16; off; off >>= 1) amax = fmaxf(amax, __shfl_xor(amax, off));
    float s = fmaxf(amax / 448.0f, 1e-12f);          // exact division, matches reference
    float q0 = fminf(fmaxf(v.x / s, -448.f), 448.f);
    float q1 = fminf(fmaxf(v.y / s, -448.f), 448.f);
    float q2 = fminf(fmaxf(v.z / s, -448.f), 448.f);
    float q3 = fminf(fmaxf(v.w / s, -448.f), 448.f);
    uint32_t pk = __builtin_amdgcn_cvt_pk_fp8_f32(q0, q1, 0, false);
    pk = __builtin_amdgcn_cvt_pk_fp8_f32(q2, q3, pk, true);
    *reinterpret_cast<uint32_t*>(xq + (size_t)row * K + kb * 128 + sub * 4) = pk;
    if (sub == 0) sxT[(size_t)kb * M + row] = s;
}

// w_q values are already on the fp8 grid -> conversion is exact. No scale folding.
__global__ void quant_w_kernel(const float* __restrict__ wq, uint8_t* __restrict__ w8) {
    size_t i = ((size_t)blockIdx.x * blockDim.x + threadIdx.x) * 8;
    float4 a = *reinterpret_cast<const float4*>(wq + i);
    float4 b = *reinterpret_cast<const float4*>(wq + i + 4);
    uint32_t lo = __builtin_amdgcn_cvt_pk_fp8_f32(a.x, a.y, 0, false);
    lo = __builtin_amdgcn_cvt_pk_fp8_f32(a.z, a.w, lo, true);
    uint32_t hi = __builtin_amdgcn_cvt_pk_fp8_f32(b.x, b.y, 0, false);
    hi = __builtin_amdgcn_cvt_pk_fp8_f32(b.z, b.w, hi, true);
    uint2 o; o.x = lo; o.y = hi;
    *reinterpret_cast<uint2*>(w8 + i) = o;
}

// ---------- 256x256 8-wave scaled-fp8 GEMM, BK=128, ONE barrier per K-tile ----------
// r3 geometry (best measured: 99 us, wave-tile 128x64, VGPR 128, no spills) plus
// ANTI-PHASED QUADRANT ORDER: SIMD s hosts waves wid=s (wr=0) and wid=s+4 (wr=1).
// wr=0 waves run quadrants (0,0)->(0,1)->(1,1)->(1,0); wr=1 waves run
// (1,1)->(1,0)->(0,0)->(0,1). r4's PMC showed MFMA+VALU+LDS pipe bills SUM to the
// wall -- lockstep waves fight for the same pipe then idle together. Anti-phasing
// pairs each MFMA burst with the partner wave's ds_read/rescale window.
// Both B-fragment sets stay live across the tile (saves 4 reads/tile vs r3).
//
// LDS column layout: 16B-slot permutation kslot (g<<1|h) -> (h<<2|g), then
// XOR-swizzle slot ^= (row&7): fragment reads hit slots {lg}^swz (lo) and
// {4|lg}^swz (hi) -- the pattern measured at ZERO bank conflicts (r3/r6/r8).
// Staging pre-permutes the GLOBAL source (rule #21).

// Stage a full 256-row x 128B tile (A or B). 4 loads/thread at 512 threads.
__device__ __forceinline__ void stageT(const uint8_t* __restrict__ g,
                                       uint8_t* l, int tid) {
    #pragma unroll
    for (int i = 0; i < 4; ++i) {
        int t2 = tid + i * 512;
        int r  = t2 >> 3;                 // 0..255
        int qs = t2 & 7;                  // dest 16B slot (linear; wave-contiguous dest)
        int s  = qs ^ (r & 7);
        int ks = ((s & 3) << 1) | (s >> 2);   // inverse perm: source k-slot
        __builtin_amdgcn_global_load_lds(
            (const GLOBAL_AS uint32_t*)(g + (size_t)r * K + (ks << 4)),
            (LDS_AS uint32_t*)(l + r * 128 + qs * 16), 16, 0, 0);
    }
}

// Fragment loads: lane group lg needs k-bytes [32lg..32lg+31] = perm slots lg (lo)
// and 4|lg (hi), each XOR'd with (row&7) == (lane&7).
#define LOAD_AF(MH, XSV)                                                          \
  _Pragma("unroll")                                                               \
  for (int m = 0; m < 4; ++m) {                                                   \
    const char* rp = (const char*)lAp + (wr * 128 + (MH) * 64 + m * 16) * 128;    \
    i32x4 lo = *(const i32x4*)(rp + loB);                                         \
    i32x4 hi = *(const i32x4*)(rp + (loB ^ 64));                                  \
    af[m] = __builtin_shufflevector(lo, hi, 0, 1, 2, 3, 4, 5, 6, 7);              \
    XSV[m] = sxl[t * 256 + wr * 128 + (MH) * 64 + m * 16 + (lane & 15)];          \
  }

#define LOAD_BF(NH, BFV)                                                          \
  _Pragma("unroll")                                                               \
  for (int n = 0; n < 2; ++n) {                                                   \
    const char* rp = (const char*)lBp + (wc * 64 + (NH) * 32 + n * 16) * 128;     \
    i32x4 lo = *(const i32x4*)(rp + loB);                                         \
    i32x4 hi = *(const i32x4*)(rp + (loB ^ 64));                                  \
    BFV[n] = __builtin_shufflevector(lo, hi, 0, 1, 2, 3, 4, 5, 6, 7);             \
  }

#define MFMA8(PD, AFV, BFV)                                                       \
  _Pragma("unroll")                                                               \
  for (int m = 0; m < 4; ++m)                                                     \
    _Pragma("unroll")                                                             \
    for (int n = 0; n < 2; ++n)                                                   \
      PD[m][n] = __builtin_amdgcn_mfma_scale_f32_16x16x128_f8f6f4(                \
          BFV[n], AFV[m], zf4, 0, 0, 0, 0x7F7F7F7F, 0, 0x7F7F7F7F);

#define RESC(PD, XSV, MH, NH)                                                     \
  _Pragma("unroll")                                                               \
  for (int m = 0; m < 4; ++m) {                                                   \
    float sm = XSV[m] * wst;                                                      \
    _Pragma("unroll")                                                             \
    for (int n = 0; n < 2; ++n)                                                   \
      acc[(MH) * 4 + m][(NH) * 2 + n] += sm * PD[m][n];                           \
  }

#define STAGE_ALL()                                                               \
  { stageT(gA, sA, tid); stageT(gB, sB, tid); }

__global__ __launch_bounds__(512, 2) void gemm_kernel(
    const uint8_t* __restrict__ A, const uint8_t* __restrict__ B,
    const float* __restrict__ sxT_g, const float* __restrict__ Ws,
    float* __restrict__ C) {
    __shared__ uint8_t lA[2][256 * 128];   // 64 KiB
    __shared__ uint8_t lB[2][256 * 128];   // 64 KiB
    __shared__ float   sxl[KBLK * 256];    // 16 KiB: x scales, [kb][block-row]
    __shared__ float   wsl[32];            // w scales for the block's 2 nb x 16 kb

    // XCD-aware bijective swizzle (512 blocks % 8 == 0)
    int cpx = gridDim.x >> 3;
    int sw  = (blockIdx.x & 7) * cpx + (blockIdx.x >> 3);
    int tm = sw & 15;                 // M/256 = 16
    int tn = sw >> 4;                 // N/256 = 32
    int row0 = tm * 256, col0 = tn * 256;

    int tid = threadIdx.x;
    int wid = tid >> 6, lane = tid & 63;
    int lg  = lane >> 4;              // k-group 0..3
    int wr = wid >> 2, wc = wid & 3;  // 2 x 4 wave grid; per-wave output 128x64
                                      // SIMD s hosts wid s (wr=0) and s+4 (wr=1)

    // per-lane fragment byte offset within a row-block: swizzled lo slot + row-in-16
    int loB = ((lg ^ (lane & 7)) << 4) + (lane & 15) * 128;

    const uint8_t* Ag = A + (size_t)row0 * K;
    const uint8_t* Bg = B + (size_t)col0 * K;

    f32x4 acc[8][4] = {};
    const f32x4 zf4 = {0.f, 0.f, 0.f, 0.f};

    // ---- prologue: scales + full tile 0; single drain ----
    if (tid < 32)
        __builtin_amdgcn_global_load_lds(
            (const GLOBAL_AS uint32_t*)(Ws + (tn * 2 + (tid >> 4)) * KBLK + (tid & 15)),
            (LDS_AS uint32_t*)(wsl + tid), 4, 0, 0);
    #pragma unroll
    for (int i = 0; i < 2; ++i) {
        int idx = tid + i * 512;
        __builtin_amdgcn_global_load_lds(
            (const GLOBAL_AS uint32_t*)(sxT_g + (size_t)(idx >> 6) * M + row0 + (idx & 63) * 4),
            (LDS_AS uint32_t*)(sxl + idx * 4), 16, 0, 0);
    }
    stageT(Ag, lA[0], tid);
    stageT(Bg, lB[0], tid);
    __syncthreads();

    for (int t = 0; t < KBLK; ++t) {
        const uint8_t* lAp = lA[t & 1];
        const uint8_t* lBp = lB[t & 1];
        uint8_t* sA = lA[(t + 1) & 1];
        uint8_t* sB = lB[(t + 1) & 1];
        int tn1 = (t + 1 < KBLK) ? (t + 1) : 0;        // clamp (unused when !stg)
        const uint8_t* gA = Ag + (size_t)tn1 * 128;
        const uint8_t* gB = Bg + (size_t)tn1 * 128;
        bool stg = (t + 1 < KBLK);
        i32x8 af[4], bf0[2], bf1[2];
        float xs0[4], xs1[4];
        float wst = wsl[(wc >> 1) * KBLK + t];

        if (wr == 0) {
            // order A: (0,0) -> (0,1) -> (1,1) -> (1,0)
            LOAD_AF(0, xs0);
            LOAD_BF(0, bf0);
            if (stg) STAGE_ALL();
            f32x4 P0[4][2]; MFMA8(P0, af, bf0);
            LOAD_BF(1, bf1);
            RESC(P0, xs0, 0, 0);
            f32x4 P1[4][2]; MFMA8(P1, af, bf1);
            LOAD_AF(1, xs1);
            RESC(P1, xs0, 0, 1);
            f32x4 P2[4][2]; MFMA8(P2, af, bf1);
            RESC(P2, xs1, 1, 1);
            f32x4 P3[4][2]; MFMA8(P3, af, bf0);
            RESC(P3, xs1, 1, 0);
        } else {
            // order B (anti-phase): (1,1) -> (1,0) -> (0,0) -> (0,1)
            LOAD_AF(1, xs1);
            LOAD_BF(1, bf1);
            if (stg) STAGE_ALL();
            f32x4 P0[4][2]; MFMA8(P0, af, bf1);
            LOAD_BF(0, bf0);
            RESC(P0, xs1, 1, 1);
            f32x4 P1[4][2]; MFMA8(P1, af, bf0);
            LOAD_AF(0, xs0);
            RESC(P1, xs1, 1, 0);
            f32x4 P2[4][2]; MFMA8(P2, af, bf0);
            RESC(P2, xs0, 0, 0);
            f32x4 P3[4][2]; MFMA8(P3, af, bf1);
            RESC(P3, xs0, 0, 1);
        }

        // single tile barrier: staging issued a full tile ago -> vmcnt drain ~free;
        // orders reads-of-cur before next tile's overwrites.
        __syncthreads();
    }

    // ---- epilogue: C write (lane&15 = M-row, regs = contiguous N-cols) ----
    #pragma unroll
    for (int m = 0; m < 8; ++m)
        #pragma unroll
        for (int j = 0; j < 4; ++j) {
            int rr = row0 + wr * 128 + m * 16 + (lane & 15);
            int cc = col0 + wc * 64 + j * 16 + (lane >> 4) * 4;
            *reinterpret_cast<f32x4*>(&C[(size_t)rr * N + cc]) = acc[m][j];
        }
}

// ---------- fallback path (small ws): exact f32, slow but correct ----------

__global__ void xs_kernel(const float* __restrict__ x, float* __restrict__ xs) {
    int task = blockIdx.x * 4 + (threadIdx.x >> 6);
    int lane = threadIdx.x & 63;
    int row = task >> 4, kb = task & 15;
    float2 v = *reinterpret_cast<const float2*>(x + (size_t)row * K + kb * 128 + lane * 2);
    float amax = fmaxf(fabsf(v.x), fabsf(v.y));
    #pragma unroll
    for (int off = 32; off; off >>= 1) amax = fmaxf(amax, __shfl_xor(amax, off));
    if (lane == 0) xs[row * KBLK + kb] = fmaxf(amax / 448.0f, 1e-12f);
}

__global__ __launch_bounds__(256) void fallback_gemm(const float* __restrict__ x,
                                                     const float* __restrict__ wq,
                                                     const float* __restrict__ wsc,
                                                     const float* __restrict__ xs,
                                                     float* __restrict__ C) {
    __shared__ float As[64][128];
    __shared__ float Bs[64][128];
    int tm = blockIdx.x % (M / 64), tn = blockIdx.x / (M / 64);
    int row0 = tm * 64, col0 = tn * 64;
    int tid = threadIdx.x;
    int tr = tid >> 4, tc = tid & 15;
    float acc[4][4] = {};
    for (int kb = 0; kb < KBLK; ++kb) {
        int k0 = kb * 128;
        __syncthreads();
        for (int t = tid * 4; t < 64 * 128; t += 256 * 4) {
            int r = t >> 7, c = t & 127;
            float4 va = *reinterpret_cast<const float4*>(x + (size_t)(row0 + r) * K + k0 + c);
            float sa = xs[(row0 + r) * KBLK + kb];
            va.x = fp8_e4m3_rne(va.x / sa) * sa; va.y = fp8_e4m3_rne(va.y / sa) * sa;
            va.z = fp8_e4m3_rne(va.z / sa) * sa; va.w = fp8_e4m3_rne(va.w / sa) * sa;
            *reinterpret_cast<float4*>(&As[r][c]) = va;
            float4 vb = *reinterpret_cast<const float4*>(wq + (size_t)(col0 + r) * K + k0 + c);
            float sb = wsc[((col0 + r) >> 7) * KBLK + kb];
            vb.x *= sb; vb.y *= sb; vb.z *= sb; vb.w *= sb;
            *reinterpret_cast<float4*>(&Bs[r][c]) = vb;
        }
        __syncthreads();
        for (int kk = 0; kk < 128; ++kk) {
            float a[4], b[4];
            #pragma unroll
            for (int i = 0; i < 4; ++i) a[i] = As[tr * 4 + i][kk];
            #pragma unroll
            for (int j = 0; j < 4; ++j) b[j] = Bs[tc * 4 + j][kk];
            #pragma unroll
            for (int i = 0; i < 4; ++i)
                #pragma unroll
                for (int j = 0; j < 4; ++j) acc[i][j] += a[i] * b[j];
        }
    }
    #pragma unroll
    for (int i = 0; i < 4; ++i)
        #pragma unroll
        for (int j = 0; j < 4; ++j)
            C[(size_t)(row0 + tr * 4 + i) * N + col0 + tc * 4 + j] = acc[i][j];
}

// ---------- launch ----------

extern "C" void kernel_launch(void* const* d_in, const int* in_sizes, int n_in,
                              void* d_out, int out_size, void* d_ws, size_t ws_size,
                              hipStream_t stream) {
    const float* x  = (const float*)d_in[0];
    const float* wq = (const float*)d_in[1];
    const float* ws = (const float*)d_in[2];
    float* out = (float*)d_out;

    size_t need_fast = (size_t)M * K + (size_t)N * K + (size_t)KBLK * M * 4;  // ~25.4 MB
    if (ws_size >= need_fast) {
        uint8_t* xq8 = (uint8_t*)d_ws;
        uint8_t* w8  = xq8 + (size_t)M * K;
        float*   sxT = (float*)(w8 + (size_t)N * K);
        quant_x_kernel<<<M * KBLK / 8, 256, 0, stream>>>(x, xq8, sxT);
        quant_w_kernel<<<(int)(((size_t)N * K / 8) / 256), 256, 0, stream>>>(wq, w8);
        gemm_kernel<<<(M / 256) * (N / 256), 512, 0, stream>>>(xq8, w8, sxT, ws, out);
    } else if (ws_size >= (size_t)M * KBLK * 4) {
        float* xs = (float*)d_ws;
        xs_kernel<<<M * KBLK / 4, 256, 0, stream>>>(x, xs);
        fallback_gemm<<<(M / 64) * (N / 64), 256, 0, stream>>>(x, wq, ws, xs, out);
    }
}

// Round 10
// 112.740 us; speedup vs baseline: 5.9214x; 5.9214x over previous
//
#include <hip/hip_runtime.h>
#include <cstdint>
#include <cstddef>

static constexpr int M = 4096, K = 2048, N = 8192;
static constexpr int KBLK = K / 128;  // 16 k-blocks of the quant scheme

#define GLOBAL_AS __attribute__((address_space(1)))
#define LDS_AS    __attribute__((address_space(3)))

typedef float f32x4 __attribute__((ext_vector_type(4)));
typedef int   i32x4 __attribute__((ext_vector_type(4)));
typedef int   i32x8 __attribute__((ext_vector_type(8)));

// ---------- numerics helpers (fallback path) ----------

__device__ inline float fp8_e4m3_rne(float a) {
    float mag = fminf(fabsf(a), 448.0f);
    float r;
    if (mag < 0.015625f) {                       // below 2^-6: subnormal quantum 2^-9
        r = rintf(mag * 512.0f) * (1.0f / 512.0f);
    } else {
        uint32_t u = __float_as_uint(mag);
        u = (u + ((u >> 20) & 1u) + 0x7FFFFu) & 0xFFF00000u;   // RNE to 3 mantissa bits
        r = fminf(__uint_as_float(u), 448.0f);
    }
    return copysignf(r, a);
}

// ---------- fused quant kernel: f32 -> raw fp8 e4m3 bytes (x AND w in one launch) ----------
// Blocks [0, XBLOCKS): x path -- per (row, 128-kblock) scale, fp8 bytes + transposed
//   scales sxT[kb][m]. Blocks [XBLOCKS, ...): w path -- plain f32->fp8 (w_q already on
//   the fp8 grid, so conversion is exact; scales stay separate).
// One launch instead of two: removes a dispatch serialization and lets both
// BW-bound streams share the HBM pipe.

static constexpr int XBLOCKS = M * KBLK / 8;                     // 8192
static constexpr int WBLOCKS = (int)(((size_t)N * K / 8) / 256); // 8192

__global__ void quant_fused_kernel(const float* __restrict__ x, uint8_t* __restrict__ xq,
                                   float* __restrict__ sxT,
                                   const float* __restrict__ wq, uint8_t* __restrict__ w8) {
    if (blockIdx.x < XBLOCKS) {
        int task = blockIdx.x * 8 + (threadIdx.x >> 5);   // 32 lanes per (row,kb) task
        int sub  = threadIdx.x & 31;
        int row = task >> 4;           // KBLK = 16
        int kb  = task & 15;
        const float* p = x + (size_t)row * K + kb * 128 + sub * 4;
        float4 v = *reinterpret_cast<const float4*>(p);
        float amax = fmaxf(fmaxf(fabsf(v.x), fabsf(v.y)), fmaxf(fabsf(v.z), fabsf(v.w)));
        #pragma unroll
        for (int off = 16; off; off >>= 1) amax = fmaxf(amax, __shfl_xor(amax, off));
        float s = fmaxf(amax / 448.0f, 1e-12f);          // exact division, matches reference
        float q0 = fminf(fmaxf(v.x / s, -448.f), 448.f);
        float q1 = fminf(fmaxf(v.y / s, -448.f), 448.f);
        float q2 = fminf(fmaxf(v.z / s, -448.f), 448.f);
        float q3 = fminf(fmaxf(v.w / s, -448.f), 448.f);
        uint32_t pk = __builtin_amdgcn_cvt_pk_fp8_f32(q0, q1, 0, false);
        pk = __builtin_amdgcn_cvt_pk_fp8_f32(q2, q3, pk, true);
        *reinterpret_cast<uint32_t*>(xq + (size_t)row * K + kb * 128 + sub * 4) = pk;
        if (sub == 0) sxT[(size_t)kb * M + row] = s;
    } else {
        size_t i = ((size_t)(blockIdx.x - XBLOCKS) * blockDim.x + threadIdx.x) * 8;
        float4 a = *reinterpret_cast<const float4*>(wq + i);
        float4 b = *reinterpret_cast<const float4*>(wq + i + 4);
        uint32_t lo = __builtin_amdgcn_cvt_pk_fp8_f32(a.x, a.y, 0, false);
        lo = __builtin_amdgcn_cvt_pk_fp8_f32(a.z, a.w, lo, true);
        uint32_t hi = __builtin_amdgcn_cvt_pk_fp8_f32(b.x, b.y, 0, false);
        hi = __builtin_amdgcn_cvt_pk_fp8_f32(b.z, b.w, hi, true);
        uint2 o; o.x = lo; o.y = hi;
        *reinterpret_cast<uint2*>(w8 + i) = o;
    }
}

// ---------- 256x256 8-wave scaled-fp8 GEMM, BK=128, ONE barrier per K-tile ----------
// VERBATIM round-3 kernel (best measured: 99 us gemm, VGPR 128, zero conflicts,
// no spills). No intra-tile barriers: all 4 quadrant passes read stable
// double-buffered LDS; the 2 waves/SIMD slip freely. Immediate per-quadrant
// rescale keeps P transient.
//
// LDS column layout: 16B-slot permutation kslot (g<<1|h) -> (h<<2|g), then
// XOR-swizzle slot ^= (row&7). Fragment reads hit slots {0..3}^swz (lo) and
// {4..7}^swz (hi) -- measured ZERO bank conflicts. Staging pre-permutes the
// GLOBAL source (rule #21).

__device__ __forceinline__ void stageA8(const uint8_t* __restrict__ g,
                                        uint8_t* l, int h, int tid) {
    #pragma unroll
    for (int i = 0; i < 2; ++i) {
        int t2 = tid + i * 512;
        int lr = t2 >> 3;                 // 0..127
        int qs = t2 & 7;                  // dest 16B slot (linear)
        int r  = (lr >> 6) * 128 + h * 64 + (lr & 63);
        int s  = qs ^ (r & 7);
        int ks = ((s & 3) << 1) | (s >> 2);   // inverse perm: source k-slot
        __builtin_amdgcn_global_load_lds(
            (const GLOBAL_AS uint32_t*)(g + (size_t)r * K + (ks << 4)),
            (LDS_AS uint32_t*)(l + r * 128 + qs * 16), 16, 0, 0);
    }
}

__device__ __forceinline__ void stageB8(const uint8_t* __restrict__ g,
                                        uint8_t* l, int h, int tid) {
    #pragma unroll
    for (int i = 0; i < 2; ++i) {
        int t2 = tid + i * 512;
        int lr = t2 >> 3;
        int qs = t2 & 7;
        int r  = (lr >> 5) * 64 + h * 32 + (lr & 31);
        int s  = qs ^ (r & 7);
        int ks = ((s & 3) << 1) | (s >> 2);
        __builtin_amdgcn_global_load_lds(
            (const GLOBAL_AS uint32_t*)(g + (size_t)r * K + (ks << 4)),
            (LDS_AS uint32_t*)(l + r * 128 + qs * 16), 16, 0, 0);
    }
}

// Fragment loads: lane lg = lane>>4 needs k-bytes [32lg..32lg+31] = perm slots lg (lo)
// and 4|lg (hi), each XOR'd with (row&7).
#define LOAD_A(MH)                                                                \
  _Pragma("unroll")                                                               \
  for (int m = 0; m < 4; ++m) {                                                   \
    int row = wr * 128 + (MH) * 64 + m * 16 + (lane & 15);                        \
    const char* rp = (const char*)lAp + row * 128;                                \
    i32x4 lo = *(const i32x4*)(rp + (((lg)     ^ (row & 7)) << 4));               \
    i32x4 hi = *(const i32x4*)(rp + (((4 | lg) ^ (row & 7)) << 4));               \
    af[m] = __builtin_shufflevector(lo, hi, 0, 1, 2, 3, 4, 5, 6, 7);              \
    xs[m] = sxl[t * 256 + wr * 128 + (MH) * 64 + m * 16 + (lane & 15)];           \
  }

#define LOAD_B(NH)                                                                \
  _Pragma("unroll")                                                               \
  for (int n = 0; n < 2; ++n) {                                                   \
    int row = wc * 64 + (NH) * 32 + n * 16 + (lane & 15);                         \
    const char* rp = (const char*)lBp + row * 128;                                \
    i32x4 lo = *(const i32x4*)(rp + (((lg)     ^ (row & 7)) << 4));               \
    i32x4 hi = *(const i32x4*)(rp + (((4 | lg) ^ (row & 7)) << 4));               \
    bfr[n] = __builtin_shufflevector(lo, hi, 0, 1, 2, 3, 4, 5, 6, 7);             \
  }

// 8 MFMAs for quadrant (MH,NH), immediate rescale into acc. P is transient.
#define QCOMP(MH, NH)                                                             \
  {                                                                               \
    f32x4 P[4][2];                                                                \
    __builtin_amdgcn_s_setprio(1);                                                \
    _Pragma("unroll")                                                             \
    for (int m = 0; m < 4; ++m)                                                   \
      _Pragma("unroll")                                                           \
      for (int n = 0; n < 2; ++n)                                                 \
        P[m][n] = __builtin_amdgcn_mfma_scale_f32_16x16x128_f8f6f4(               \
            bfr[n], af[m], zf4, 0, 0, 0, 0x7F7F7F7F, 0, 0x7F7F7F7F);              \
    __builtin_amdgcn_s_setprio(0);                                                \
    _Pragma("unroll")                                                             \
    for (int m = 0; m < 4; ++m) {                                                 \
      float sm = xs[m] * wst;                                                     \
      _Pragma("unroll")                                                           \
      for (int n = 0; n < 2; ++n)                                                 \
        acc[(MH) * 4 + m][(NH) * 2 + n] += sm * P[m][n];                          \
    }                                                                             \
  }

__global__ __launch_bounds__(512, 2) void gemm_kernel(
    const uint8_t* __restrict__ A, const uint8_t* __restrict__ B,
    const float* __restrict__ sxT_g, const float* __restrict__ Ws,
    float* __restrict__ C) {
    __shared__ uint8_t lA[2][256 * 128];   // 64 KiB
    __shared__ uint8_t lB[2][256 * 128];   // 64 KiB
    __shared__ float   sxl[KBLK * 256];    // 16 KiB: x scales, [kb][block-row]
    __shared__ float   wsl[32];            // w scales for the block's 2 nb x 16 kb

    // XCD-aware bijective swizzle (512 blocks % 8 == 0)
    int cpx = gridDim.x >> 3;
    int sw  = (blockIdx.x & 7) * cpx + (blockIdx.x >> 3);
    int tm = sw & 15;                 // M/256 = 16
    int tn = sw >> 4;                 // N/256 = 32
    int row0 = tm * 256, col0 = tn * 256;

    int tid = threadIdx.x;
    int wid = tid >> 6, lane = tid & 63;
    int lg  = lane >> 4;              // k-group 0..3
    int wr = wid >> 2, wc = wid & 3;  // 2 x 4 wave grid; per-wave output 128x64

    const uint8_t* Ag = A + (size_t)row0 * K;
    const uint8_t* Bg = B + (size_t)col0 * K;

    f32x4 acc[8][4] = {};
    const f32x4 zf4 = {0.f, 0.f, 0.f, 0.f};

    // ---- prologue: scales + full tile 0; single drain ----
    if (tid < 32)
        __builtin_amdgcn_global_load_lds(
            (const GLOBAL_AS uint32_t*)(Ws + (tn * 2 + (tid >> 4)) * KBLK + (tid & 15)),
            (LDS_AS uint32_t*)(wsl + tid), 4, 0, 0);
    #pragma unroll
    for (int i = 0; i < 2; ++i) {
        int idx = tid + i * 512;
        __builtin_amdgcn_global_load_lds(
            (const GLOBAL_AS uint32_t*)(sxT_g + (size_t)(idx >> 6) * M + row0 + (idx & 63) * 4),
            (LDS_AS uint32_t*)(sxl + idx * 4), 16, 0, 0);
    }
    stageA8(Ag, lA[0], 0, tid);
    stageA8(Ag, lA[0], 1, tid);
    stageB8(Bg, lB[0], 0, tid);
    stageB8(Bg, lB[0], 1, tid);
    __syncthreads();

    for (int t = 0; t < KBLK; ++t) {
        const uint8_t* lAp = lA[t & 1];
        const uint8_t* lBp = lB[t & 1];
        uint8_t* sA = lA[(t + 1) & 1];
        uint8_t* sB = lB[(t + 1) & 1];
        int tn1 = (t + 1 < KBLK) ? (t + 1) : 0;        // clamp (unused when !stg)
        const uint8_t* gA = Ag + (size_t)tn1 * 128;
        const uint8_t* gB = Bg + (size_t)tn1 * 128;
        bool stg = (t + 1 < KBLK);
        i32x8 af[4], bfr[2];
        float xs[4];
        float wst = wsl[(wc >> 1) * KBLK + t];

        // q0: (0,0) — load A-frags + B-frags; stage next A-h0 + B-h0 early
        LOAD_A(0); LOAD_B(0);
        if (stg) { stageA8(gA, sA, 0, tid); stageB8(gB, sB, 0, tid); }
        QCOMP(0, 0);
        // q1: (0,1) — reuse af, load bfr; stage next B-h1
        LOAD_B(1);
        if (stg) stageB8(gB, sB, 1, tid);
        QCOMP(0, 1);
        // q2: (1,1) — load af, reuse bfr; stage next A-h1
        LOAD_A(1);
        if (stg) stageA8(gA, sA, 1, tid);
        QCOMP(1, 1);
        // q3: (1,0) — reuse af, load bfr
        LOAD_B(0);
        QCOMP(1, 0);

        // single tile barrier: drains vmcnt (staging landed, issued >=1 quadrant ago)
        // and orders reads-of-cur before next tile's overwrites.
        __syncthreads();
    }

    // ---- epilogue: C write (lane&15 = M-row, regs = contiguous N-cols) ----
    #pragma unroll
    for (int m = 0; m < 8; ++m)
        #pragma unroll
        for (int j = 0; j < 4; ++j) {
            int rr = row0 + wr * 128 + m * 16 + (lane & 15);
            int cc = col0 + wc * 64 + j * 16 + (lane >> 4) * 4;
            *reinterpret_cast<f32x4*>(&C[(size_t)rr * N + cc]) = acc[m][j];
        }
}

// ---------- fallback path (small ws): exact f32, slow but correct ----------

__global__ void xs_kernel(const float* __restrict__ x, float* __restrict__ xs) {
    int task = blockIdx.x * 4 + (threadIdx.x >> 6);
    int lane = threadIdx.x & 63;
    int row = task >> 4, kb = task & 15;
    float2 v = *reinterpret_cast<const float2*>(x + (size_t)row * K + kb * 128 + lane * 2);
    float amax = fmaxf(fabsf(v.x), fabsf(v.y));
    #pragma unroll
    for (int off = 32; off; off >>= 1) amax = fmaxf(amax, __shfl_xor(amax, off));
    if (lane == 0) xs[row * KBLK + kb] = fmaxf(amax / 448.0f, 1e-12f);
}

__global__ __launch_bounds__(256) void fallback_gemm(const float* __restrict__ x,
                                                     const float* __restrict__ wq,
                                                     const float* __restrict__ wsc,
                                                     const float* __restrict__ xs,
                                                     float* __restrict__ C) {
    __shared__ float As[64][128];
    __shared__ float Bs[64][128];
    int tm = blockIdx.x % (M / 64), tn = blockIdx.x / (M / 64);
    int row0 = tm * 64, col0 = tn * 64;
    int tid = threadIdx.x;
    int tr = tid >> 4, tc = tid & 15;
    float acc[4][4] = {};
    for (int kb = 0; kb < KBLK; ++kb) {
        int k0 = kb * 128;
        __syncthreads();
        for (int t = tid * 4; t < 64 * 128; t += 256 * 4) {
            int r = t >> 7, c = t & 127;
            float4 va = *reinterpret_cast<const float4*>(x + (size_t)(row0 + r) * K + k0 + c);
            float sa = xs[(row0 + r) * KBLK + kb];
            va.x = fp8_e4m3_rne(va.x / sa) * sa; va.y = fp8_e4m3_rne(va.y / sa) * sa;
            va.z = fp8_e4m3_rne(va.z / sa) * sa; va.w = fp8_e4m3_rne(va.w / sa) * sa;
            *reinterpret_cast<float4*>(&As[r][c]) = va;
            float4 vb = *reinterpret_cast<const float4*>(wq + (size_t)(col0 + r) * K + k0 + c);
            float sb = wsc[((col0 + r) >> 7) * KBLK + kb];
            vb.x *= sb; vb.y *= sb; vb.z *= sb; vb.w *= sb;
            *reinterpret_cast<float4*>(&Bs[r][c]) = vb;
        }
        __syncthreads();
        for (int kk = 0; kk < 128; ++kk) {
            float a[4], b[4];
            #pragma unroll
            for (int i = 0; i < 4; ++i) a[i] = As[tr * 4 + i][kk];
            #pragma unroll
            for (int j = 0; j < 4; ++j) b[j] = Bs[tc * 4 + j][kk];
            #pragma unroll
            for (int i = 0; i < 4; ++i)
                #pragma unroll
                for (int j = 0; j < 4; ++j) acc[i][j] += a[i] * b[j];
        }
    }
    #pragma unroll
    for (int i = 0; i < 4; ++i)
        #pragma unroll
        for (int j = 0; j < 4; ++j)
            C[(size_t)(row0 + tr * 4 + i) * N + col0 + tc * 4 + j] = acc[i][j];
}

// ---------- launch ----------

extern "C" void kernel_launch(void* const* d_in, const int* in_sizes, int n_in,
                              void* d_out, int out_size, void* d_ws, size_t ws_size,
                              hipStream_t stream) {
    const float* x  = (const float*)d_in[0];
    const float* wq = (const float*)d_in[1];
    const float* ws = (const float*)d_in[2];
    float* out = (float*)d_out;

    size_t need_fast = (size_t)M * K + (size_t)N * K + (size_t)KBLK * M * 4;  // ~25.4 MB
    if (ws_size >= need_fast) {
        uint8_t* xq8 = (uint8_t*)d_ws;
        uint8_t* w8  = xq8 + (size_t)M * K;
        float*   sxT = (float*)(w8 + (size_t)N * K);
        quant_fused_kernel<<<XBLOCKS + WBLOCKS, 256, 0, stream>>>(x, xq8, sxT, wq, w8);
        gemm_kernel<<<(M / 256) * (N / 256), 512, 0, stream>>>(xq8, w8, sxT, ws, out);
    } else if (ws_size >= (size_t)M * KBLK * 4) {
        float* xs = (float*)d_ws;
        xs_kernel<<<M * KBLK / 4, 256, 0, stream>>>(x, xs);
        fallback_gemm<<<(M / 64) * (N / 64), 256, 0, stream>>>(x, wq, ws, xs, out);
    }
}